// Round 1
// baseline (258.492 us; speedup 1.0000x reference)
//
#include <hip/hip_runtime.h>
#include <hip/hip_bf16.h>

#define BATCH 4
#define SEQ 2048
#define EMBED 512
#define NHEAD 8
#define HDIM 64
#define MTOT (BATCH*SEQ)   // 8192

typedef __attribute__((ext_vector_type(8))) short short8;
typedef __attribute__((ext_vector_type(4))) short short4v;
typedef __attribute__((ext_vector_type(4))) float f32x4;

#define GLOBAL_AS __attribute__((address_space(1)))
#define LDS_AS __attribute__((address_space(3)))

__device__ __forceinline__ void gload_lds16(const void* g, void* l) {
  __builtin_amdgcn_global_load_lds((const GLOBAL_AS void*)g, (LDS_AS void*)l, 16, 0, 0);
}

__device__ __forceinline__ unsigned short f2bf(float x) {
  unsigned u = __builtin_bit_cast(unsigned, x);
  unsigned r = (u + 0x7FFFu + ((u >> 16) & 1u)) >> 16;
  return (unsigned short)r;
}

__device__ __forceinline__ short8 pack8(f32x4 a, f32x4 b) {
  short8 s;
  s[0]=(short)f2bf(a[0]); s[1]=(short)f2bf(a[1]); s[2]=(short)f2bf(a[2]); s[3]=(short)f2bf(a[3]);
  s[4]=(short)f2bf(b[0]); s[5]=(short)f2bf(b[1]); s[6]=(short)f2bf(b[2]); s[7]=(short)f2bf(b[3]);
  return s;
}

// ---------------- weight convert fp32 -> bf16 ----------------
__global__ __launch_bounds__(256) void k_cvt(const float* __restrict__ src,
                                             unsigned short* __restrict__ dst, int n4) {
  int i = blockIdx.x * 256 + threadIdx.x;
  if (i < n4) {
    f32x4 f = ((const f32x4*)src)[i];
    short4v s;
    s[0]=(short)f2bf(f[0]); s[1]=(short)f2bf(f[1]); s[2]=(short)f2bf(f[2]); s[3]=(short)f2bf(f[3]);
    ((short4v*)dst)[i] = s;
  }
}

// ---------------- fused input projection GEMM ----------------
// z=0: Q = (query@Wq^T + bq) * log2e/8  -> Qg [b,h,s,d]
// z=1: K = key@Wk^T + bk               -> Kg [b,h,s,d]
// z=2: V = value@Wv^T + bv             -> VTg [b,h,d,s]  (transposed)
__global__ __launch_bounds__(256) void k_proj(
    const float* __restrict__ query, const float* __restrict__ key,
    const float* __restrict__ value, const unsigned short* __restrict__ Wbf,
    const float* __restrict__ bias,
    unsigned short* __restrict__ Qg, unsigned short* __restrict__ Kg,
    unsigned short* __restrict__ VTg) {
  __shared__ __align__(16) unsigned short As[128 * 64];
  __shared__ __align__(16) unsigned short Bs[128 * 64];
  const int tid = threadIdx.x;
  const int lane = tid & 63, w = tid >> 6;
  const int wr = w >> 1, wc = w & 1;
  const int m0 = blockIdx.x * 128, n0 = blockIdx.y * 128, z = blockIdx.z;
  const float* X = (z == 0) ? query : (z == 1) ? key : value;

  f32x4 acc[4][4];
#pragma unroll
  for (int a = 0; a < 4; ++a)
#pragma unroll
    for (int b = 0; b < 4; ++b) acc[a][b] = (f32x4){0.f, 0.f, 0.f, 0.f};

  for (int kt = 0; kt < 8; ++kt) {
    // stage A (fp32 -> bf16 via regs, swizzled ds_write)
#pragma unroll
    for (int i = 0; i < 4; ++i) {
      int cid = i * 256 + tid;
      int row = cid >> 3, c = cid & 7;
      const float* ap = X + (size_t)(m0 + row) * EMBED + kt * 64 + c * 8;
      f32x4 f0 = *(const f32x4*)ap;
      f32x4 f1 = *(const f32x4*)(ap + 4);
      *(short8*)((char*)As + row * 128 + ((c ^ (row & 7)) << 4)) = pack8(f0, f1);
    }
    // stage B (bf16 weights) via global_load_lds with pre-swizzled source
#pragma unroll
    for (int i = 0; i < 4; ++i) {
      int cb = w * 256 + i * 64;
      int chunk = cb + lane;
      int row = chunk >> 3, cs = chunk & 7;
      gload_lds16(Wbf + (size_t)(z * EMBED + n0 + row) * EMBED + kt * 64 + ((cs ^ (row & 7)) << 3),
                  (char*)Bs + cb * 16);
    }
    __syncthreads();
#pragma unroll
    for (int kk = 0; kk < 2; ++kk) {
      short8 af[4], bfr[4];
      int dc = kk * 4 + (lane >> 4);
#pragma unroll
      for (int mf = 0; mf < 4; ++mf) {
        int row = wr * 64 + mf * 16 + (lane & 15);
        af[mf] = *(const short8*)((const char*)As + row * 128 + ((dc ^ (row & 7)) << 4));
      }
#pragma unroll
      for (int nf = 0; nf < 4; ++nf) {
        int row = wc * 64 + nf * 16 + (lane & 15);
        bfr[nf] = *(const short8*)((const char*)Bs + row * 128 + ((dc ^ (row & 7)) << 4));
      }
#pragma unroll
      for (int mf = 0; mf < 4; ++mf)
#pragma unroll
        for (int nf = 0; nf < 4; ++nf)
          acc[mf][nf] = __builtin_amdgcn_mfma_f32_16x16x32_bf16(af[mf], bfr[nf], acc[mf][nf], 0, 0, 0);
    }
    __syncthreads();
  }

  const float SCALE = 0.18033688011112042f;  // log2(e)/8
#pragma unroll
  for (int mf = 0; mf < 4; ++mf) {
#pragma unroll
    for (int nf = 0; nf < 4; ++nf) {
      int ncol = n0 + wc * 64 + nf * 16 + (lane & 15);
      float bv = bias[z * EMBED + ncol];
      int h = ncol >> 6, dd = ncol & 63;
      if (z == 2) {
        int mrow0 = m0 + wr * 64 + mf * 16 + (lane >> 4) * 4;
        int b = mrow0 >> 11, s0 = mrow0 & 2047;
        short4v pv;
#pragma unroll
        for (int r = 0; r < 4; ++r) pv[r] = (short)f2bf(acc[mf][nf][r] + bv);
        *(short4v*)(VTg + ((size_t)(b * NHEAD + h) * HDIM + dd) * SEQ + s0) = pv;
      } else {
        unsigned short* dst = (z == 0) ? Qg : Kg;
        float sc = (z == 0) ? SCALE : 1.0f;
#pragma unroll
        for (int r = 0; r < 4; ++r) {
          int mrow = m0 + wr * 64 + mf * 16 + (lane >> 4) * 4 + r;
          int b = mrow >> 11, s = mrow & 2047;
          dst[((size_t)(b * NHEAD + h) * SEQ + s) * HDIM + dd] = f2bf((acc[mf][nf][r] + bv) * sc);
        }
      }
    }
  }
}

// ---------------- flash attention ----------------
// grid: (SEQ/64, B*H). 4 waves, each owns 16 q-rows. KV tile = 128.
__global__ __launch_bounds__(256) void k_attn(
    const unsigned short* __restrict__ Qg, const unsigned short* __restrict__ Kg,
    const unsigned short* __restrict__ VTg, unsigned short* __restrict__ AO) {
  __shared__ __align__(16) unsigned short Kl[128 * 64];   // [key][d] swizzled
  __shared__ __align__(16) unsigned short Vl[64 * 128];   // [d][key] swizzled
  __shared__ __align__(16) unsigned short Pl[4 * 16 * 128];
  const int tid = threadIdx.x, lane = tid & 63, w = tid >> 6;
  const int bh = blockIdx.y, q0 = blockIdx.x * 64;

  short8 qf[2];
  {
    int qrow = q0 + w * 16 + (lane & 15);
    const unsigned short* qp = Qg + ((size_t)bh * SEQ + qrow) * HDIM + (lane >> 4) * 8;
    qf[0] = *(const short8*)qp;
    qf[1] = *(const short8*)(qp + 32);
  }

  f32x4 o[4];
  float m_run[4], l_run[4];
#pragma unroll
  for (int n = 0; n < 4; ++n) o[n] = (f32x4){0.f, 0.f, 0.f, 0.f};
#pragma unroll
  for (int r = 0; r < 4; ++r) { m_run[r] = -__builtin_inff(); l_run[r] = 0.f; }

  char* Pb = (char*)Pl + w * 4096;

  for (int t = 0; t < 16; ++t) {
    const int kv0 = t * 128;
#pragma unroll
    for (int i = 0; i < 4; ++i) {
      int cb = w * 256 + i * 64;
      int chunk = cb + lane;
      {
        int row = chunk >> 3, cs = chunk & 7;
        gload_lds16(Kg + ((size_t)bh * SEQ + kv0 + row) * HDIM + ((cs ^ (row & 7)) << 3),
                    (char*)Kl + cb * 16);
      }
      {
        int d = chunk >> 4, kc = chunk & 15;
        gload_lds16(VTg + ((size_t)bh * HDIM + d) * SEQ + kv0 + ((kc ^ (d & 7)) << 3),
                    (char*)Vl + cb * 16);
      }
    }
    __syncthreads();

    // S = Q K^T (pre-scaled by log2e/8 via Q)
    f32x4 sf[8];
#pragma unroll
    for (int j = 0; j < 8; ++j) {
      int key = j * 16 + (lane & 15);
      int dc0 = (lane >> 4), dc1 = 4 + (lane >> 4);
      short8 k0 = *(const short8*)((char*)Kl + key * 128 + ((dc0 ^ (key & 7)) << 4));
      short8 k1 = *(const short8*)((char*)Kl + key * 128 + ((dc1 ^ (key & 7)) << 4));
      f32x4 z4 = (f32x4){0.f, 0.f, 0.f, 0.f};
      z4 = __builtin_amdgcn_mfma_f32_16x16x32_bf16(qf[0], k0, z4, 0, 0, 0);
      sf[j] = __builtin_amdgcn_mfma_f32_16x16x32_bf16(qf[1], k1, z4, 0, 0, 0);
    }

    // online softmax
    float alpha[4], rs[4];
#pragma unroll
    for (int r = 0; r < 4; ++r) {
      float v = sf[0][r];
#pragma unroll
      for (int j = 1; j < 8; ++j) v = fmaxf(v, sf[j][r]);
      v = fmaxf(v, __shfl_xor(v, 1));
      v = fmaxf(v, __shfl_xor(v, 2));
      v = fmaxf(v, __shfl_xor(v, 4));
      v = fmaxf(v, __shfl_xor(v, 8));
      float mn = fmaxf(m_run[r], v);
      alpha[r] = exp2f(m_run[r] - mn);
      m_run[r] = mn;
      rs[r] = 0.f;
    }
#pragma unroll
    for (int j = 0; j < 8; ++j)
#pragma unroll
      for (int r = 0; r < 4; ++r) {
        float p = exp2f(sf[j][r] - m_run[r]);
        sf[j][r] = p;
        rs[r] += p;
      }
#pragma unroll
    for (int r = 0; r < 4; ++r) {
      rs[r] += __shfl_xor(rs[r], 1);
      rs[r] += __shfl_xor(rs[r], 2);
      rs[r] += __shfl_xor(rs[r], 4);
      rs[r] += __shfl_xor(rs[r], 8);
      l_run[r] = l_run[r] * alpha[r] + rs[r];
    }
#pragma unroll
    for (int n = 0; n < 4; ++n)
#pragma unroll
      for (int r = 0; r < 4; ++r) o[n][r] *= alpha[r];

    // P -> LDS (bf16, swizzled) to reach MFMA A-layout
#pragma unroll
    for (int j = 0; j < 8; ++j) {
      int col = j * 16 + (lane & 15);
      int cch = col >> 3;
#pragma unroll
      for (int r = 0; r < 4; ++r) {
        int row = (lane >> 4) * 4 + r;
        *(unsigned short*)(Pb + row * 256 + ((cch ^ (row & 7)) << 4) + (col & 7) * 2) =
            f2bf(sf[j][r]);
      }
    }

    // O += P V
#pragma unroll
    for (int kk = 0; kk < 4; ++kk) {
      int prow = lane & 15;
      int kch = kk * 4 + (lane >> 4);
      short8 pa = *(const short8*)(Pb + prow * 256 + ((kch ^ (prow & 7)) << 4));
#pragma unroll
      for (int n = 0; n < 4; ++n) {
        int d = n * 16 + (lane & 15);
        short8 vf = *(const short8*)((char*)Vl + d * 256 + ((kch ^ (d & 7)) << 4));
        o[n] = __builtin_amdgcn_mfma_f32_16x16x32_bf16(pa, vf, o[n], 0, 0, 0);
      }
    }
    __syncthreads();
  }

  const int h = bh & 7, bb = bh >> 3;
#pragma unroll
  for (int r = 0; r < 4; ++r) {
    float inv = 1.0f / l_run[r];
    int srow = q0 + w * 16 + (lane >> 4) * 4 + r;
#pragma unroll
    for (int n = 0; n < 4; ++n) {
      int e = h * 64 + n * 16 + (lane & 15);
      AO[((size_t)(bb * SEQ) + srow) * EMBED + e] = f2bf(o[n][r] * inv);
    }
  }
}

// ---------------- output projection GEMM ----------------
__global__ __launch_bounds__(256) void k_outproj(
    const unsigned short* __restrict__ AO, const unsigned short* __restrict__ Wo,
    const float* __restrict__ bias, float* __restrict__ out) {
  __shared__ __align__(16) unsigned short As[128 * 64];
  __shared__ __align__(16) unsigned short Bs[128 * 64];
  const int tid = threadIdx.x;
  const int lane = tid & 63, w = tid >> 6;
  const int wr = w >> 1, wc = w & 1;
  const int m0 = blockIdx.x * 128, n0 = blockIdx.y * 128;

  f32x4 acc[4][4];
#pragma unroll
  for (int a = 0; a < 4; ++a)
#pragma unroll
    for (int b = 0; b < 4; ++b) acc[a][b] = (f32x4){0.f, 0.f, 0.f, 0.f};

  for (int kt = 0; kt < 8; ++kt) {
#pragma unroll
    for (int i = 0; i < 4; ++i) {
      int cb = w * 256 + i * 64;
      int chunk = cb + lane;
      int row = chunk >> 3, cs = chunk & 7;
      gload_lds16(AO + (size_t)(m0 + row) * EMBED + kt * 64 + ((cs ^ (row & 7)) << 3),
                  (char*)As + cb * 16);
      gload_lds16(Wo + (size_t)(n0 + row) * EMBED + kt * 64 + ((cs ^ (row & 7)) << 3),
                  (char*)Bs + cb * 16);
    }
    __syncthreads();
#pragma unroll
    for (int kk = 0; kk < 2; ++kk) {
      short8 af[4], bfr[4];
      int dc = kk * 4 + (lane >> 4);
#pragma unroll
      for (int mf = 0; mf < 4; ++mf) {
        int row = wr * 64 + mf * 16 + (lane & 15);
        af[mf] = *(const short8*)((const char*)As + row * 128 + ((dc ^ (row & 7)) << 4));
      }
#pragma unroll
      for (int nf = 0; nf < 4; ++nf) {
        int row = wc * 64 + nf * 16 + (lane & 15);
        bfr[nf] = *(const short8*)((const char*)Bs + row * 128 + ((dc ^ (row & 7)) << 4));
      }
#pragma unroll
      for (int mf = 0; mf < 4; ++mf)
#pragma unroll
        for (int nf = 0; nf < 4; ++nf)
          acc[mf][nf] = __builtin_amdgcn_mfma_f32_16x16x32_bf16(af[mf], bfr[nf], acc[mf][nf], 0, 0, 0);
    }
    __syncthreads();
  }

#pragma unroll
  for (int mf = 0; mf < 4; ++mf)
#pragma unroll
    for (int nf = 0; nf < 4; ++nf) {
      int ncol = n0 + wc * 64 + nf * 16 + (lane & 15);
      float bv = bias[ncol];
#pragma unroll
      for (int r = 0; r < 4; ++r) {
        int mrow = m0 + wr * 64 + mf * 16 + (lane >> 4) * 4 + r;
        out[(size_t)mrow * EMBED + ncol] = acc[mf][nf][r] + bv;
      }
    }
}

extern "C" void kernel_launch(void* const* d_in, const int* in_sizes, int n_in,
                              void* d_out, int out_size, void* d_ws, size_t ws_size,
                              hipStream_t stream) {
  const float* query = (const float*)d_in[0];
  const float* key   = (const float*)d_in[1];
  const float* value = (const float*)d_in[2];
  const float* win   = (const float*)d_in[3];
  const float* bin   = (const float*)d_in[4];
  const float* wout  = (const float*)d_in[5];
  const float* bout  = (const float*)d_in[6];
  float* out = (float*)d_out;

  char* ws = (char*)d_ws;
  unsigned short* Wbf  = (unsigned short*)(ws);              // 1.5 MB
  unsigned short* Wobf = (unsigned short*)(ws + 0x180000);   // 0.5 MB
  unsigned short* Qg   = (unsigned short*)(ws + 0x200000);   // 8 MB
  unsigned short* Kg   = (unsigned short*)(ws + 0xA00000);   // 8 MB
  unsigned short* VTg  = (unsigned short*)(ws + 0x1200000);  // 8 MB
  unsigned short* AO   = (unsigned short*)(ws + 0x1A00000);  // 8 MB

  k_cvt<<<768, 256, 0, stream>>>(win, Wbf, 196608);
  k_cvt<<<256, 256, 0, stream>>>(wout, Wobf, 65536);
  k_proj<<<dim3(64, 4, 3), 256, 0, stream>>>(query, key, value, Wbf, bin, Qg, Kg, VTg);
  k_attn<<<dim3(32, 32), 256, 0, stream>>>(Qg, Kg, VTg, AO);
  k_outproj<<<dim3(64, 4), 256, 0, stream>>>(AO, Wobf, bout, out);
}